// Round 9
// baseline (191.300 us; speedup 1.0000x reference)
//
#include <hip/hip_runtime.h>

#define T_SEQ 2048
#define DM 1024
#define NH 16
#define HD 64
// SCALE * log2(e) : softmax computed in exp2 domain (folded into Q in qkv_gemm)
#define SC2 0.1803368801111731f

typedef unsigned short u16;
typedef unsigned int u32;
typedef __attribute__((ext_vector_type(8))) short bf16x8;
typedef __attribute__((ext_vector_type(4))) float f32x4;

static __device__ __forceinline__ f32x4 mfma16(bf16x8 a, bf16x8 b, f32x4 c) {
    return __builtin_amdgcn_mfma_f32_16x16x32_bf16(a, b, c, 0, 0, 0);
}
static __device__ __forceinline__ float bf2f(u16 u) {
    union { u32 i; float f; } v; v.i = ((u32)u) << 16; return v.f;
}
static __device__ __forceinline__ u16 f2bf(float f) {
    union { float f; u32 i; } v; v.f = f;
    u32 x = v.i;
    x += 0x7FFFu + ((x >> 16) & 1u);   // RNE
    return (u16)(x >> 16);
}
static __device__ __forceinline__ u16 f2bf_t(float f) {   // truncating (1 op)
    union { float f; u32 i; } v; v.f = f;
    return (u16)(v.i >> 16);
}
static __device__ __forceinline__ u32 pk2(float lo, float hi) {
    return (u32)f2bf(lo) | ((u32)f2bf(hi) << 16);
}
static __device__ __forceinline__ float ex2(float x) {
    return __builtin_amdgcn_exp2f(x);
}

// Async global->LDS DMA, 16 B per lane.
static __device__ __forceinline__ void gl16(const u16* g, u16* l) {
    __builtin_amdgcn_global_load_lds(
        (const __attribute__((address_space(1))) void*)g,
        (__attribute__((address_space(3))) void*)l,
        16, 0, 0);
}

// ---------------------------------------------------------------------------
// Staging into unpadded LDS (row stride 64 u16 = 128 B) with XOR chunk
// swizzle: LDS slot (r, c) holds global chunk c^(r&7). Global side fully
// coalesced; b128 fragment reads land 2-way (free).
// r5/r6 lesson: V direct-to-register loads lose 10-18us vs this path.
// r3/r4 lesson: occupancy is the latency hider -- never spend blocks/CU.
// ---------------------------------------------------------------------------
template <int NISS>
static __device__ __forceinline__ void stage_async(const u16* src, size_t row0,
                                                   size_t lds_, size_t col0,
                                                   u16* dst, int tid) {
#pragma unroll
    for (int it = 0; it < NISS; it++) {
        int r = it * 32 + (tid >> 3);
        int cg = (tid & 7) ^ (r & 7);
        gl16(&src[(row0 + r) * lds_ + col0 + cg * 8], &dst[(it * 256 + tid) * 8]);
    }
}
// r8: G-permuted K staging for swapped-QK attn. LDS row r holds GLOBAL row
// G(r) = (j>>1)*32 + (j&1)*4 + (m>>2)*8 + (m&3)  (r = j*16+m; bijection).
// Reads stay at rows j*16+lr with the standard co swizzle, and the P value
// held by output reg (j,quad,reg) has k_local = (j>>1)*32+(j&1)*4+quad*8+reg
// -- exactly the contiguous k-chunk the PV A-fragment needs per lane.
static __device__ __forceinline__ void stage_perm(const u16* src, size_t row0,
                                                  u16* dst, int tid) {
#pragma unroll
    for (int it = 0; it < 2; it++) {
        int r = it * 32 + (tid >> 3);
        int jj = r >> 4, m = r & 15;
        int gr = (jj >> 1) * 32 + (jj & 1) * 4 + (m >> 2) * 8 + (m & 3);
        int cg = (tid & 7) ^ (r & 7);
        gl16(&src[(row0 + gr) * HD + cg * 8], &dst[(it * 256 + tid) * 8]);
    }
}
static __device__ __forceinline__ bf16x8 frag(const u16* buf, int R, int co) {
    return *(const bf16x8*)(&buf[R * 64 + co]);
}

// ---------------------------------------------------------------------------
// detect_dtype: ONE block. in_sizes are ELEMENT counts (r1 lesson), so dtype
// must be probed on-device. flag=1 means bf16.
// ---------------------------------------------------------------------------
__global__ __launch_bounds__(256) void detect_dtype(const u16* __restrict__ x,
                                                    int* __restrict__ flag) {
    __shared__ int tot;
    const int tid = threadIdx.x;
    if (tid == 0) tot = 0;
    __syncthreads();
    int c = 0;
#pragma unroll
    for (int i = 0; i < 4; i++) {
        u16 v = x[2 * (tid * 4 + i)];
        int e = (v >> 7) & 0xFF;
        c += (e >= 110 && e <= 140) ? 1 : 0;
    }
    atomicAdd(&tot, c);
    __syncthreads();
    if (tid == 0) *flag = (tot >= 512) ? 1 : 0;
}

// ---------------------------------------------------------------------------
// cvt_bf16: one-pass f32 -> bf16 (RNE) conversion for x + 5 weight mats.
// Early-exits when flag says input is already bf16.
// ---------------------------------------------------------------------------
__global__ __launch_bounds__(256) void cvt_bf16(
    const int* __restrict__ flag,
    const float* __restrict__ x, const float* __restrict__ wq,
    const float* __restrict__ wk1, const float* __restrict__ wk2,
    const float* __restrict__ wv, const float* __restrict__ wo,
    u16* __restrict__ xc, u16* __restrict__ wqc, u16* __restrict__ wk1c,
    u16* __restrict__ wk2c, u16* __restrict__ wvc, u16* __restrict__ woc) {
    if (*flag) return;   // input already bf16 -- nothing to convert
    const int b = blockIdx.x;
    const int tid = threadIdx.x;
    const float* src;
    u16* dst;
    int rel;
    if (b < 1024)      { src = x;   dst = xc;   rel = b; }
    else if (b < 1536) { src = wq;  dst = wqc;  rel = b - 1024; }
    else if (b < 2048) { src = wk1; dst = wk1c; rel = b - 1536; }
    else if (b < 2560) { src = wk2; dst = wk2c; rel = b - 2048; }
    else if (b < 3072) { src = wv;  dst = wvc;  rel = b - 2560; }
    else               { src = wo;  dst = woc;  rel = b - 3072; }
    size_t idx = (size_t)rel * 2048 + (size_t)tid * 8;
    const float* s = src + idx;
    uint4 a = *(const uint4*)s;
    uint4 bq = *(const uint4*)(s + 4);
    const float* af = (const float*)&a;
    const float* bf = (const float*)&bq;
    uint4 r;
    r.x = pk2(af[0], af[1]); r.y = pk2(af[2], af[3]);
    r.z = pk2(bf[0], bf[1]); r.w = pk2(bf[2], bf[3]);
    *(uint4*)(dst + idx) = r;
}

// ---------------------------------------------------------------------------
// QKV(+V-transpose) projection GEMM. Tile 128x128xK64, async DMA dbuf
// (64 KB LDS -> 2 blocks/CU; grid 512). (unchanged)
// ---------------------------------------------------------------------------
__global__ __launch_bounds__(256) void qkv_gemm(
    const int* __restrict__ flag,
    const void* __restrict__ x0, const void* __restrict__ wq0,
    const void* __restrict__ wk10, const void* __restrict__ wk20,
    const void* __restrict__ wv0,
    const u16* __restrict__ xc, const u16* __restrict__ wqc,
    const u16* __restrict__ wk1c, const u16* __restrict__ wk2c,
    const u16* __restrict__ wvc,
    u16* __restrict__ qd, u16* __restrict__ k1d, u16* __restrict__ k2d,
    u16* __restrict__ vtd) {
    __shared__ __align__(16) u16 As[2][128 * 64];
    __shared__ __align__(16) u16 Bs[2][128 * 64];

    const int f = *flag;   // 1 = inputs already bf16
    const int tid = threadIdx.x;
    const int w = blockIdx.x >> 3;
    const int n0 = (blockIdx.x & 7) * 128;
    const int m0 = blockIdx.y * 128;
    const u16* xb = f ? (const u16*)x0 : xc;
    const u16* Bb;
    if (w == 0)      Bb = f ? (const u16*)wq0  : wqc;
    else if (w == 1) Bb = f ? (const u16*)wk10 : wk1c;
    else if (w == 2) Bb = f ? (const u16*)wk20 : wk2c;
    else             Bb = f ? (const u16*)wv0  : wvc;

    const int lane = tid & 63, wave = tid >> 6;
    const int lr = lane & 15, quad = lane >> 4;
    const int wm = (wave >> 1) * 64, wn = (wave & 1) * 64;
    const int sw = lr & 7;

    f32x4 acc[4][4];
#pragma unroll
    for (int i = 0; i < 4; i++)
#pragma unroll
        for (int j = 0; j < 4; j++) acc[i][j] = (f32x4){0.f, 0.f, 0.f, 0.f};

    stage_async<4>(xb, m0, DM, 0, As[0], tid);
    stage_async<4>(Bb, n0, DM, 0, Bs[0], tid);
    for (int k0 = 0; k0 < DM; k0 += 64) {
        const int cur = (k0 >> 6) & 1;
        __syncthreads();   // drains vmcnt -> tile cur resident; prev readers done
        if (k0 + 64 < DM) {
            stage_async<4>(xb, m0, DM, k0 + 64, As[cur ^ 1], tid);
            stage_async<4>(Bb, n0, DM, k0 + 64, Bs[cur ^ 1], tid);
        }
#pragma unroll
        for (int kk = 0; kk < 2; kk++) {
            const int co = ((kk * 4 + quad) ^ sw) * 8;
            bf16x8 af[4], bfr[4];
#pragma unroll
            for (int i = 0; i < 4; i++) af[i] = frag(As[cur], wm + i * 16 + lr, co);
#pragma unroll
            for (int j = 0; j < 4; j++) bfr[j] = frag(Bs[cur], wn + j * 16 + lr, co);
#pragma unroll
            for (int i = 0; i < 4; i++)
#pragma unroll
                for (int j = 0; j < 4; j++) acc[i][j] = mfma16(af[i], bfr[j], acc[i][j]);
        }
    }

#pragma unroll
    for (int i = 0; i < 4; i++)
#pragma unroll
        for (int j = 0; j < 4; j++)
#pragma unroll
            for (int r = 0; r < 4; r++) {
                int t = m0 + wm + i * 16 + quad * 4 + r;
                int o = n0 + wn + j * 16 + lr;
                float val = acc[i][j][r];
                if (w == 0) val *= SC2;               // fold softmax scale into Q
                u16 vbits = f2bf(val);
                int hh = o >> 6, d0 = o & 63;
                if (w == 3)
                    vtd[((size_t)hh * HD + d0) * T_SEQ + t] = vbits;   // v transposed
                else
                    ((w == 0) ? qd : (w == 1) ? k1d : k2d)[((size_t)hh * T_SEQ + t) * HD + d0] = vbits;
            }
}

// ---------------------------------------------------------------------------
// XCD-paired block mapping (r7, neutral-harmless): XCD x = blockIdx%8 serves
// heads {2x, 2x+1}. qt balance pairing {qt, 31-qt} kept.
// r8: SWAPPED QK^T -- S[k][q] = mfma(K_frag, Q_frag); each thread owns one
// q-row (q = lr); P stays in registers between QK and PV.
// ---------------------------------------------------------------------------
#define ATTN_MAP_COMMON()                                     \
    const int tid = threadIdx.x;                              \
    const int lane = tid & 63, wave = tid >> 6;               \
    const int lr = lane & 15, quad = lane >> 4;               \
    const int wm = wave * 16;                                 \
    const int sw = lr & 7;

// ---------------------------------------------------------------------------
// attn_a: partial Z1/Z2 over the kt ≡ par (mod 4) strip. Grid 2048 ->
// 8 blocks/CU (16 KB LDS). zp: [par*2+which][NH][T] f32. (r8 version)
// ---------------------------------------------------------------------------
__global__ __launch_bounds__(256) void attn_a(
    const u16* __restrict__ qg, const u16* __restrict__ k1g,
    const u16* __restrict__ k2g, float* __restrict__ zp) {
    __shared__ __align__(16) u16 k1s[64 * 64];
    __shared__ __align__(16) u16 k2s[64 * 64];
    const int b = blockIdx.x;
    const int x = b & 7;                 // XCD slot
    const int g = b >> 3;                // 0..255
    const int hl = g >> 7;               // 0..1
    const int par = (g >> 5) & 3;        // 0..3
    const int bi = g & 31;
    const int qt = (bi < 16) ? bi : 47 - bi;
    const int h = x * 2 + hl;
    const int t0 = qt * 64;
    ATTN_MAP_COMMON();

    const u16* qh = qg + (size_t)h * T_SEQ * HD;
    const u16* k1h = k1g + (size_t)h * T_SEQ * HD;
    const u16* k2h = k2g + (size_t)h * T_SEQ * HD;

    const int qrow = t0 + wm + lr;       // this thread's q-row (swapped layout)
    bf16x8 aq[2];
#pragma unroll
    for (int kb = 0; kb < 2; kb++)
        aq[kb] = *(const bf16x8*)(&qh[(size_t)qrow * HD + kb * 32 + quad * 8]);

    float z1 = 0.f, z2 = 0.f;

    for (int kt = par; kt <= qt; kt += 4) {
        __syncthreads();   // protect LDS from previous iteration's readers
        stage_perm(k1h, (size_t)kt * 64, k1s, tid);
        stage_perm(k2h, (size_t)kt * 64, k2s, tid);
        __syncthreads();   // drains vmcnt -> data visible

        f32x4 sa[4], sb[4];
#pragma unroll
        for (int j = 0; j < 4; j++) { sa[j] = (f32x4){0.f,0.f,0.f,0.f}; sb[j] = (f32x4){0.f,0.f,0.f,0.f}; }
#pragma unroll
        for (int kb = 0; kb < 2; kb++) {
            const int co = ((kb * 4 + quad) ^ sw) * 8;
#pragma unroll
            for (int j = 0; j < 4; j++) {
                sa[j] = mfma16(frag(k1s, j * 16 + lr, co), aq[kb], sa[j]);
                sb[j] = mfma16(frag(k2s, j * 16 + lr, co), aq[kb], sb[j]);
            }
        }

        if (kt < qt) {
#pragma unroll
            for (int j = 0; j < 4; j++)
#pragma unroll
                for (int r = 0; r < 4; r++) {
                    z1 += ex2(sa[j][r]);
                    z2 += ex2(sb[j][r]);
                }
        } else {
#pragma unroll
            for (int j = 0; j < 4; j++)
#pragma unroll
                for (int r = 0; r < 4; r++) {
                    int kglob = kt * 64 + (j >> 1) * 32 + (j & 1) * 4 + quad * 8 + r;
                    if (kglob <= qrow) {
                        z1 += ex2(sa[j][r]);
                        z2 += ex2(sb[j][r]);
                    }
                }
        }
    }

    // reduce across the 4 quads holding the same q-row
    z1 += __shfl_xor(z1, 16, 64); z1 += __shfl_xor(z1, 32, 64);
    z2 += __shfl_xor(z2, 16, 64); z2 += __shfl_xor(z2, 32, 64);
    if (quad == 0) {
        zp[((size_t)(par * 2 + 0) * NH + h) * T_SEQ + qrow] = z1;
        zp[((size_t)(par * 2 + 1) * NH + h) * T_SEQ + qrow] = z2;
    }
}

// ---------------------------------------------------------------------------
// attn_b r9: K1/K2 double-buffered (32 KB) + V single-buffered (8 KB) =
// 40960 B = EXACTLY 4 blocks/CU (dbuf at full residency -- enabled by r8
// deleting ps). Per iteration: syncthreads (drains K[cur], landed under the
// previous iteration) -> issue V[kt] then K[kt+2] prefetch -> QK + softmax
// (V lands under this) -> s_waitcnt vmcnt(4) (drain V only; vmcnt(0) on
// last iter, block-uniform) + sched_barrier + s_barrier -> PV.
// K-stage latency fully hidden; V gets ~400cy of cover.
// ---------------------------------------------------------------------------
__global__ __launch_bounds__(256) void attn_b(
    const u16* __restrict__ qg, const u16* __restrict__ k1g,
    const u16* __restrict__ k2g, const u16* __restrict__ vtg,
    const float* __restrict__ zp, const void* __restrict__ lamsrc,
    const int* __restrict__ flag,
    float* __restrict__ dpart, u16* __restrict__ opart) {
    __shared__ __align__(16) u16 k1s[2][64 * 64];   // 16 KB
    __shared__ __align__(16) u16 k2s[2][64 * 64];   // 16 KB
    __shared__ __align__(16) u16 vs[64 * 64];       //  8 KB -> 40960 B
    const int b = blockIdx.x;
    const int x = b & 7;                 // XCD slot
    const int g = b >> 3;                // 0..127
    const int hl = g >> 6;               // 0..1
    const int par = (g >> 5) & 1;        // 0..1
    const int bi = g & 31;
    const int qt = (bi < 16) ? bi : 47 - bi;
    const int h = x * 2 + hl;
    const int t0 = qt * 64;
    ATTN_MAP_COMMON();

    const int f = *flag;
    float lamlogit = f ? bf2f(((const u16*)lamsrc)[h]) : ((const float*)lamsrc)[h];
    const float lam = 1.0f / (1.0f + __expf(-lamlogit));

    const u16* qh = qg + (size_t)h * T_SEQ * HD;
    const u16* k1h = k1g + (size_t)h * T_SEQ * HD;
    const u16* k2h = k2g + (size_t)h * T_SEQ * HD;
    const u16* vh = vtg + (size_t)h * HD * T_SEQ;

    const int qrow = t0 + wm + lr;       // this thread's q-row for P
    bf16x8 aq[2];
#pragma unroll
    for (int kb = 0; kb < 2; kb++)
        aq[kb] = *(const bf16x8*)(&qh[(size_t)qrow * HD + kb * 32 + quad * 8]);

    float zz1 = 0.f, zz2 = 0.f;
#pragma unroll
    for (int p = 0; p < 4; p++) {
        zz1 += zp[((size_t)(p * 2 + 0) * NH + h) * T_SEQ + qrow];
        zz2 += zp[((size_t)(p * 2 + 1) * NH + h) * T_SEQ + qrow];
    }
    const float z1l = -__log2f(zz1);
    const float z2l = __log2f(lam) - __log2f(zz2);

    f32x4 oac[4];
#pragma unroll
    for (int j = 0; j < 4; j++) oac[j] = (f32x4){0.f, 0.f, 0.f, 0.f};
    float dacc = 0.f;

    stage_perm(k1h, (size_t)par * 64, k1s[0], tid);
    stage_perm(k2h, (size_t)par * 64, k2s[0], tid);
    int cur = 0;
    for (int kt = par; kt <= qt; kt += 2) {
        __syncthreads();   // drains K[cur] (landed under prev iter); fences vs

        // V for THIS tile (issued first -> oldest in vmcnt order)
        stage_async<2>(vh, 0, T_SEQ, (size_t)kt * 64, vs, tid);
        const bool pf = (kt + 2 <= qt);  // block-uniform
        if (pf) {
            stage_perm(k1h, (size_t)(kt + 2) * 64, k1s[cur ^ 1], tid);
            stage_perm(k2h, (size_t)(kt + 2) * 64, k2s[cur ^ 1], tid);
        }

        f32x4 sa[4], sb[4];
#pragma unroll
        for (int j = 0; j < 4; j++) { sa[j] = (f32x4){0.f,0.f,0.f,0.f}; sb[j] = (f32x4){0.f,0.f,0.f,0.f}; }
#pragma unroll
        for (int kb = 0; kb < 2; kb++) {
            const int co = ((kb * 4 + quad) ^ sw) * 8;
#pragma unroll
            for (int j = 0; j < 4; j++) {
                sa[j] = mfma16(frag(k1s[cur], j * 16 + lr, co), aq[kb], sa[j]);
                sb[j] = mfma16(frag(k2s[cur], j * 16 + lr, co), aq[kb], sb[j]);
            }
        }

        // softmax-difference, all in registers; pt[kh][e] with
        // e = (j&1)*4 + r, k_local = kh*32 + quad*8 + e
        float pt[2][8];
        if (kt < qt) {
#pragma unroll
            for (int j = 0; j < 4; j++)
#pragma unroll
                for (int r = 0; r < 4; r++) {
                    float pv = ex2(sa[j][r] + z1l) - ex2(sb[j][r] + z2l);
                    dacc += fabsf(pv);
                    pt[j >> 1][(j & 1) * 4 + r] = pv;
                }
        } else {
#pragma unroll
            for (int j = 0; j < 4; j++)
#pragma unroll
                for (int r = 0; r < 4; r++) {
                    int kglob = kt * 64 + (j >> 1) * 32 + (j & 1) * 4 + quad * 8 + r;
                    float pv = 0.f;
                    if (kglob <= qrow)
                        pv = ex2(sa[j][r] + z1l) - ex2(sb[j][r] + z2l);
                    dacc += fabsf(pv);
                    pt[j >> 1][(j & 1) * 4 + r] = pv;
                }
        }

        // pack P A-fragments (registers only; truncating bf16 as before)
        bf16x8 pa[2];
#pragma unroll
        for (int kh = 0; kh < 2; kh++) {
            union { u32 w[4]; bf16x8 v; } pk_;
#pragma unroll
            for (int wi = 0; wi < 4; wi++)
                pk_.w[wi] = (u32)f2bf_t(pt[kh][2 * wi]) |
                            ((u32)f2bf_t(pt[kh][2 * wi + 1]) << 16);
            pa[kh] = pk_.v;
        }

        // pre-PV: drain V (leave K prefetch in flight), then block barrier so
        // ALL waves' V writes are visible. vmcnt(4) = K prefetch outstanding.
        if (pf) asm volatile("s_waitcnt vmcnt(4)" ::: "memory");
        else    asm volatile("s_waitcnt vmcnt(0)" ::: "memory");
        __builtin_amdgcn_sched_barrier(0);   // rule #18: fence against hoisting
        __builtin_amdgcn_s_barrier();

        // PV: A = P (in regs), B = V fragments from LDS
#pragma unroll
        for (int kh = 0; kh < 2; kh++) {
            const int co = ((kh * 4 + quad) ^ sw) * 8;
#pragma unroll
            for (int j = 0; j < 4; j++)
                oac[j] = mfma16(pa[kh], frag(vs, j * 16 + lr, co), oac[j]);
        }
        cur ^= 1;
    }

    // denom reduce across quads (same q-row), write by quad 0
    float ds = dacc;
    ds += __shfl_xor(ds, 16, 64);
    ds += __shfl_xor(ds, 32, 64);
    if (quad == 0)
        dpart[((size_t)par * NH + h) * T_SEQ + qrow] = ds;

#pragma unroll
    for (int j = 0; j < 4; j++)
#pragma unroll
        for (int r = 0; r < 4; r++) {
            int row = t0 + wm + quad * 4 + r;
            opart[(size_t)par * T_SEQ * DM + (size_t)row * DM + h * HD + j * 16 + lr] =
                f2bf(oac[j][r]);
        }
}

// ---------------------------------------------------------------------------
// normalize: ao[t][d] = (O0+O1) / max(d0+d1, 1e-6).
// ---------------------------------------------------------------------------
__global__ __launch_bounds__(256) void normalize_o(
    const u16* __restrict__ opart, const float* __restrict__ dpart,
    u16* __restrict__ ao) {
    int g = blockIdx.x * 256 + threadIdx.x;
    int t = g >> 7;
    int cc = g & 127;
    int d0 = cc * 8;
    int h = d0 >> 6;
    float dsum = dpart[(size_t)h * T_SEQ + t] + dpart[(size_t)(NH + h) * T_SEQ + t];
    float rs = 1.f / fmaxf(dsum, 1e-6f);
    uint4 a = *(const uint4*)(&opart[(size_t)t * DM + d0]);
    uint4 bqq = *(const uint4*)(&opart[(size_t)T_SEQ * DM + (size_t)t * DM + d0]);
    const u32* au = (const u32*)&a;
    const u32* bu = (const u32*)&bqq;
    uint4 out;
    u32* ou = (u32*)&out;
#pragma unroll
    for (int i = 0; i < 4; i++) {
        float lo = (bf2f((u16)(au[i] & 0xFFFF)) + bf2f((u16)(bu[i] & 0xFFFF))) * rs;
        float hi = (bf2f((u16)(au[i] >> 16)) + bf2f((u16)(bu[i] >> 16))) * rs;
        ou[i] = pk2(lo, hi);
    }
    *(uint4*)(&ao[(size_t)t * DM + d0]) = out;
}

// ---------------------------------------------------------------------------
// Output GEMM: out = ao @ Wo^T. Tile 64x64 -> grid (16,32) = 512 blocks =
// 2 blocks/CU. Always-async dbuf staging. (unchanged)
// ---------------------------------------------------------------------------
__global__ __launch_bounds__(256) void out_gemm(
    const u16* __restrict__ ab, const void* __restrict__ wo0,
    const u16* __restrict__ woc, const int* __restrict__ flag,
    void* __restrict__ outp) {
    __shared__ __align__(16) u16 As[2][64 * 64];
    __shared__ __align__(16) u16 Bs[2][64 * 64];

    const int f = *flag;   // 1 = bf16 in/out
    const u16* wb = f ? (const u16*)wo0 : woc;
    const int n0 = blockIdx.x * 64;    // 0..15
    const int m0 = blockIdx.y * 64;    // 0..31
    const int tid = threadIdx.x;
    const int lane = tid & 63, wave = tid >> 6;
    const int lr = lane & 15, quad = lane >> 4;
    const int wm = (wave >> 1) * 32, wn = (wave & 1) * 32;
    const int sw = lr & 7;

    f32x4 acc[2][2];
#pragma unroll
    for (int i = 0; i < 2; i++)
#pragma unroll
        for (int j = 0; j < 2; j++) acc[i][j] = (f32x4){0.f, 0.f, 0.f, 0.f};

    stage_async<2>(ab, m0, DM, 0, As[0], tid);
    stage_async<2>(wb, n0, DM, 0, Bs[0], tid);
    for (int k0 = 0; k0 < DM; k0 += 64) {
        const int cur = (k0 >> 6) & 1;
        __syncthreads();
        if (k0 + 64 < DM) {
            stage_async<2>(ab, m0, DM, k0 + 64, As[cur ^ 1], tid);
            stage_async<2>(wb, n0, DM, k0 + 64, Bs[cur ^ 1], tid);
        }
#pragma unroll
        for (int kk = 0; kk < 2; kk++) {
            const int co = ((kk * 4 + quad) ^ sw) * 8;
            bf16x8 af[2], bfr[2];
#pragma unroll
            for (int i = 0; i < 2; i++) af[i] = frag(As[cur], wm + i * 16 + lr, co);
#pragma unroll
            for (int j = 0; j < 2; j++) bfr[j] = frag(Bs[cur], wn + j * 16 + lr, co);
#pragma unroll
            for (int i = 0; i < 2; i++)
#pragma unroll
                for (int j = 0; j < 2; j++) acc[i][j] = mfma16(af[i], bfr[j], acc[i][j]);
        }
    }

#pragma unroll
    for (int i = 0; i < 2; i++)
#pragma unroll
        for (int j = 0; j < 2; j++)
#pragma unroll
            for (int r = 0; r < 4; r++) {
                int t = m0 + wm + i * 16 + quad * 4 + r;
                int o = n0 + wn + j * 16 + lr;
                float val = acc[i][j][r];
                if (f)
                    ((u16*)outp)[(size_t)t * DM + o] = f2bf(val);
                else
                    ((float*)outp)[(size_t)t * DM + o] = val;
            }
}

extern "C" void kernel_launch(void* const* d_in, const int* in_sizes, int n_in,
                              void* d_out, int out_size, void* d_ws, size_t ws_size,
                              hipStream_t stream) {
    char* ws = (char*)d_ws;
    int* flag = (int*)(ws + 0);
    float* zp    = (float*)(ws + ((size_t)1 << 20));   // [8][NH][T] f32 = 1 MB
    float* dpart = (float*)(ws + ((size_t)2 << 20));   // [2][NH][T] f32
    u16* qd  = (u16*)(ws + ((size_t)16 << 20));  // [H][T][64]
    u16* k1d = (u16*)(ws + ((size_t)20 << 20));
    u16* k2d = (u16*)(ws + ((size_t)24 << 20));
    u16* vtd = (u16*)(ws + ((size_t)28 << 20));  // [H][64][T]
    u16* ao  = (u16*)(ws + ((size_t)32 << 20));  // [T][DM] bf16
    u16* opart = (u16*)(ws + ((size_t)36 << 20)); // [2][T][DM] bf16
    // bf16-converted inputs (only written when source is f32)
    u16* xc   = (u16*)(ws + ((size_t)44 << 20)); // [T][DM]   4 MB
    u16* wqc  = (u16*)(ws + ((size_t)48 << 20)); // [DM][DM]  2 MB each
    u16* wk1c = (u16*)(ws + ((size_t)50 << 20));
    u16* wk2c = (u16*)(ws + ((size_t)52 << 20));
    u16* wvc  = (u16*)(ws + ((size_t)54 << 20));
    u16* woc  = (u16*)(ws + ((size_t)56 << 20));

    detect_dtype<<<dim3(1), 256, 0, stream>>>((const u16*)d_in[0], flag);
    cvt_bf16<<<dim3(3584), 256, 0, stream>>>(
        flag, (const float*)d_in[0], (const float*)d_in[1], (const float*)d_in[2],
        (const float*)d_in[3], (const float*)d_in[4], (const float*)d_in[5],
        xc, wqc, wk1c, wk2c, wvc, woc);
    qkv_gemm<<<dim3(32, 16), 256, 0, stream>>>(
        flag, d_in[0], d_in[1], d_in[2], d_in[3], d_in[4],
        xc, wqc, wk1c, wk2c, wvc, qd, k1d, k2d, vtd);
    attn_a<<<dim3(2048), 256, 0, stream>>>(qd, k1d, k2d, zp);
    attn_b<<<dim3(1024), 256, 0, stream>>>(qd, k1d, k2d, vtd, zp, d_in[6], flag,
                                           dpart, opart);
    normalize_o<<<dim3(1024), 256, 0, stream>>>(opart, dpart, ao);
    out_gemm<<<dim3(16, 32), 256, 0, stream>>>(ao, d_in[5], woc, flag, d_out);
}

// Round 10
// 186.158 us; speedup vs baseline: 1.0276x; 1.0276x over previous
//
#include <hip/hip_runtime.h>

#define T_SEQ 2048
#define DM 1024
#define NH 16
#define HD 64
// SCALE * log2(e) : softmax computed in exp2 domain (folded into Q in qkv_gemm)
#define SC2 0.1803368801111731f

typedef unsigned short u16;
typedef unsigned int u32;
typedef __attribute__((ext_vector_type(8))) short bf16x8;
typedef __attribute__((ext_vector_type(4))) float f32x4;

static __device__ __forceinline__ f32x4 mfma16(bf16x8 a, bf16x8 b, f32x4 c) {
    return __builtin_amdgcn_mfma_f32_16x16x32_bf16(a, b, c, 0, 0, 0);
}
static __device__ __forceinline__ float bf2f(u16 u) {
    union { u32 i; float f; } v; v.i = ((u32)u) << 16; return v.f;
}
static __device__ __forceinline__ u16 f2bf(float f) {
    union { float f; u32 i; } v; v.f = f;
    u32 x = v.i;
    x += 0x7FFFu + ((x >> 16) & 1u);   // RNE
    return (u16)(x >> 16);
}
static __device__ __forceinline__ u16 f2bf_t(float f) {   // truncating (1 op)
    union { float f; u32 i; } v; v.f = f;
    return (u16)(v.i >> 16);
}
static __device__ __forceinline__ u32 pk2(float lo, float hi) {
    return (u32)f2bf(lo) | ((u32)f2bf(hi) << 16);
}
static __device__ __forceinline__ float ex2(float x) {
    return __builtin_amdgcn_exp2f(x);
}

// Async global->LDS DMA, 16 B per lane.
static __device__ __forceinline__ void gl16(const u16* g, u16* l) {
    __builtin_amdgcn_global_load_lds(
        (const __attribute__((address_space(1))) void*)g,
        (__attribute__((address_space(3))) void*)l,
        16, 0, 0);
}

// ---------------------------------------------------------------------------
// Staging into unpadded LDS (row stride 64 u16 = 128 B) with XOR chunk
// swizzle: LDS slot (r, c) holds global chunk c^(r&7). Global side fully
// coalesced; b128 fragment reads land 2-way (free).
// r5/r6 lesson: V direct-to-register loads lose 10-18us vs this path.
// r3/r4/r9 lesson: occupancy is the latency hider; schedule-axis changes
// (dbuf, counted vmcnt) are neutral at best in these attn kernels.
// ---------------------------------------------------------------------------
template <int NISS>
static __device__ __forceinline__ void stage_async(const u16* src, size_t row0,
                                                   size_t lds_, size_t col0,
                                                   u16* dst, int tid) {
#pragma unroll
    for (int it = 0; it < NISS; it++) {
        int r = it * 32 + (tid >> 3);
        int cg = (tid & 7) ^ (r & 7);
        gl16(&src[(row0 + r) * lds_ + col0 + cg * 8], &dst[(it * 256 + tid) * 8]);
    }
}
// r8: G-permuted K staging for swapped-QK attn. LDS row r holds GLOBAL row
// G(r) = (j>>1)*32 + (j&1)*4 + (m>>2)*8 + (m&3)  (r = j*16+m; bijection).
// Reads stay at rows j*16+lr with the standard co swizzle, and the P value
// held by output reg (j,quad,reg) has k_local = (j>>1)*32+(j&1)*4+quad*8+reg
// -- exactly the contiguous k-chunk the PV A-fragment needs per lane.
static __device__ __forceinline__ void stage_perm(const u16* src, size_t row0,
                                                  u16* dst, int tid) {
#pragma unroll
    for (int it = 0; it < 2; it++) {
        int r = it * 32 + (tid >> 3);
        int jj = r >> 4, m = r & 15;
        int gr = (jj >> 1) * 32 + (jj & 1) * 4 + (m >> 2) * 8 + (m & 3);
        int cg = (tid & 7) ^ (r & 7);
        gl16(&src[(row0 + gr) * HD + cg * 8], &dst[(it * 256 + tid) * 8]);
    }
}
static __device__ __forceinline__ bf16x8 frag(const u16* buf, int R, int co) {
    return *(const bf16x8*)(&buf[R * 64 + co]);
}

// ---------------------------------------------------------------------------
// detect_dtype: ONE block. in_sizes are ELEMENT counts (r1 lesson), so dtype
// must be probed on-device. flag=1 means bf16.
// ---------------------------------------------------------------------------
__global__ __launch_bounds__(256) void detect_dtype(const u16* __restrict__ x,
                                                    int* __restrict__ flag) {
    __shared__ int tot;
    const int tid = threadIdx.x;
    if (tid == 0) tot = 0;
    __syncthreads();
    int c = 0;
#pragma unroll
    for (int i = 0; i < 4; i++) {
        u16 v = x[2 * (tid * 4 + i)];
        int e = (v >> 7) & 0xFF;
        c += (e >= 110 && e <= 140) ? 1 : 0;
    }
    atomicAdd(&tot, c);
    __syncthreads();
    if (tid == 0) *flag = (tot >= 512) ? 1 : 0;
}

// ---------------------------------------------------------------------------
// cvt_bf16: one-pass f32 -> bf16 (RNE) conversion for x + 5 weight mats.
// Early-exits when flag says input is already bf16.
// ---------------------------------------------------------------------------
__global__ __launch_bounds__(256) void cvt_bf16(
    const int* __restrict__ flag,
    const float* __restrict__ x, const float* __restrict__ wq,
    const float* __restrict__ wk1, const float* __restrict__ wk2,
    const float* __restrict__ wv, const float* __restrict__ wo,
    u16* __restrict__ xc, u16* __restrict__ wqc, u16* __restrict__ wk1c,
    u16* __restrict__ wk2c, u16* __restrict__ wvc, u16* __restrict__ woc) {
    if (*flag) return;   // input already bf16 -- nothing to convert
    const int b = blockIdx.x;
    const int tid = threadIdx.x;
    const float* src;
    u16* dst;
    int rel;
    if (b < 1024)      { src = x;   dst = xc;   rel = b; }
    else if (b < 1536) { src = wq;  dst = wqc;  rel = b - 1024; }
    else if (b < 2048) { src = wk1; dst = wk1c; rel = b - 1536; }
    else if (b < 2560) { src = wk2; dst = wk2c; rel = b - 2048; }
    else if (b < 3072) { src = wv;  dst = wvc;  rel = b - 2560; }
    else               { src = wo;  dst = woc;  rel = b - 3072; }
    size_t idx = (size_t)rel * 2048 + (size_t)tid * 8;
    const float* s = src + idx;
    uint4 a = *(const uint4*)s;
    uint4 bq = *(const uint4*)(s + 4);
    const float* af = (const float*)&a;
    const float* bf = (const float*)&bq;
    uint4 r;
    r.x = pk2(af[0], af[1]); r.y = pk2(af[2], af[3]);
    r.z = pk2(bf[0], bf[1]); r.w = pk2(bf[2], bf[3]);
    *(uint4*)(dst + idx) = r;
}

// ---------------------------------------------------------------------------
// QKV(+V-transpose) projection GEMM. Tile 128x128xK64, async DMA dbuf
// (64 KB LDS -> 2 blocks/CU; grid 512).
// r10: XCD-localized block remap. Old mapping put one n-slice of ALL FOUR
// weights + all x rows on each XCD (~5 MB > 4 MB L2 -> streaming evictions,
// r0 FETCH 41 MB vs 24 ideal). New mapping: XCD slot k = flat%8 chooses
// w = k>>1 (ONE weight matrix, 2 MB) and m-half = k&1 (2 MB of x) = exactly
// 4 MB/XCD; 64 on-XCD blocks reuse the same weight panel. Pure bijection.
// ---------------------------------------------------------------------------
__global__ __launch_bounds__(256) void qkv_gemm(
    const int* __restrict__ flag,
    const void* __restrict__ x0, const void* __restrict__ wq0,
    const void* __restrict__ wk10, const void* __restrict__ wk20,
    const void* __restrict__ wv0,
    const u16* __restrict__ xc, const u16* __restrict__ wqc,
    const u16* __restrict__ wk1c, const u16* __restrict__ wk2c,
    const u16* __restrict__ wvc,
    u16* __restrict__ qd, u16* __restrict__ k1d, u16* __restrict__ k2d,
    u16* __restrict__ vtd) {
    __shared__ __align__(16) u16 As[2][128 * 64];
    __shared__ __align__(16) u16 Bs[2][128 * 64];

    const int f = *flag;   // 1 = inputs already bf16
    const int tid = threadIdx.x;
    // XCD-localized decode (r10): flat -> (w, m0, n0)
    const int flat = blockIdx.x + (blockIdx.y << 5);   // [0,512)
    const int k = flat & 7;          // XCD slot (empirical flat%8 round-robin)
    const int s = flat >> 3;         // 0..63 on-XCD index
    const int w = k >> 1;            // one weight matrix per XCD pair
    const int m0 = (((k & 1) << 3) | (s >> 3)) * 128;  // m-half by XCD parity
    const int n0 = (s & 7) * 128;
    const u16* xb = f ? (const u16*)x0 : xc;
    const u16* Bb;
    if (w == 0)      Bb = f ? (const u16*)wq0  : wqc;
    else if (w == 1) Bb = f ? (const u16*)wk10 : wk1c;
    else if (w == 2) Bb = f ? (const u16*)wk20 : wk2c;
    else             Bb = f ? (const u16*)wv0  : wvc;

    const int lane = tid & 63, wave = tid >> 6;
    const int lr = lane & 15, quad = lane >> 4;
    const int wm = (wave >> 1) * 64, wn = (wave & 1) * 64;
    const int sw = lr & 7;

    f32x4 acc[4][4];
#pragma unroll
    for (int i = 0; i < 4; i++)
#pragma unroll
        for (int j = 0; j < 4; j++) acc[i][j] = (f32x4){0.f, 0.f, 0.f, 0.f};

    stage_async<4>(xb, m0, DM, 0, As[0], tid);
    stage_async<4>(Bb, n0, DM, 0, Bs[0], tid);
    for (int k0 = 0; k0 < DM; k0 += 64) {
        const int cur = (k0 >> 6) & 1;
        __syncthreads();   // drains vmcnt -> tile cur resident; prev readers done
        if (k0 + 64 < DM) {
            stage_async<4>(xb, m0, DM, k0 + 64, As[cur ^ 1], tid);
            stage_async<4>(Bb, n0, DM, k0 + 64, Bs[cur ^ 1], tid);
        }
#pragma unroll
        for (int kk = 0; kk < 2; kk++) {
            const int co = ((kk * 4 + quad) ^ sw) * 8;
            bf16x8 af[4], bfr[4];
#pragma unroll
            for (int i = 0; i < 4; i++) af[i] = frag(As[cur], wm + i * 16 + lr, co);
#pragma unroll
            for (int j = 0; j < 4; j++) bfr[j] = frag(Bs[cur], wn + j * 16 + lr, co);
#pragma unroll
            for (int i = 0; i < 4; i++)
#pragma unroll
                for (int j = 0; j < 4; j++) acc[i][j] = mfma16(af[i], bfr[j], acc[i][j]);
        }
    }

#pragma unroll
    for (int i = 0; i < 4; i++)
#pragma unroll
        for (int j = 0; j < 4; j++)
#pragma unroll
            for (int r = 0; r < 4; r++) {
                int t = m0 + wm + i * 16 + quad * 4 + r;
                int o = n0 + wn + j * 16 + lr;
                float val = acc[i][j][r];
                if (w == 0) val *= SC2;               // fold softmax scale into Q
                u16 vbits = f2bf(val);
                int hh = o >> 6, d0 = o & 63;
                if (w == 3)
                    vtd[((size_t)hh * HD + d0) * T_SEQ + t] = vbits;   // v transposed
                else
                    ((w == 0) ? qd : (w == 1) ? k1d : k2d)[((size_t)hh * T_SEQ + t) * HD + d0] = vbits;
            }
}

// ---------------------------------------------------------------------------
// XCD-paired block mapping (r7, neutral-harmless): XCD x = blockIdx%8 serves
// heads {2x, 2x+1}. qt balance pairing {qt, 31-qt} kept.
// r8: SWAPPED QK^T -- S[k][q] = mfma(K_frag, Q_frag); each thread owns one
// q-row (q = lr); P stays in registers between QK and PV.
// ---------------------------------------------------------------------------
#define ATTN_MAP_COMMON()                                     \
    const int tid = threadIdx.x;                              \
    const int lane = tid & 63, wave = tid >> 6;               \
    const int lr = lane & 15, quad = lane >> 4;               \
    const int wm = wave * 16;                                 \
    const int sw = lr & 7;

// ---------------------------------------------------------------------------
// attn_a: partial Z1/Z2 over the kt ≡ par (mod 4) strip. Grid 2048 ->
// 8 blocks/CU (16 KB LDS). zp: [par*2+which][NH][T] f32. (r8 version)
// ---------------------------------------------------------------------------
__global__ __launch_bounds__(256) void attn_a(
    const u16* __restrict__ qg, const u16* __restrict__ k1g,
    const u16* __restrict__ k2g, float* __restrict__ zp) {
    __shared__ __align__(16) u16 k1s[64 * 64];
    __shared__ __align__(16) u16 k2s[64 * 64];
    const int b = blockIdx.x;
    const int x = b & 7;                 // XCD slot
    const int g = b >> 3;                // 0..255
    const int hl = g >> 7;               // 0..1
    const int par = (g >> 5) & 3;        // 0..3
    const int bi = g & 31;
    const int qt = (bi < 16) ? bi : 47 - bi;
    const int h = x * 2 + hl;
    const int t0 = qt * 64;
    ATTN_MAP_COMMON();

    const u16* qh = qg + (size_t)h * T_SEQ * HD;
    const u16* k1h = k1g + (size_t)h * T_SEQ * HD;
    const u16* k2h = k2g + (size_t)h * T_SEQ * HD;

    const int qrow = t0 + wm + lr;       // this thread's q-row (swapped layout)
    bf16x8 aq[2];
#pragma unroll
    for (int kb = 0; kb < 2; kb++)
        aq[kb] = *(const bf16x8*)(&qh[(size_t)qrow * HD + kb * 32 + quad * 8]);

    float z1 = 0.f, z2 = 0.f;

    for (int kt = par; kt <= qt; kt += 4) {
        __syncthreads();   // protect LDS from previous iteration's readers
        stage_perm(k1h, (size_t)kt * 64, k1s, tid);
        stage_perm(k2h, (size_t)kt * 64, k2s, tid);
        __syncthreads();   // drains vmcnt -> data visible

        f32x4 sa[4], sb[4];
#pragma unroll
        for (int j = 0; j < 4; j++) { sa[j] = (f32x4){0.f,0.f,0.f,0.f}; sb[j] = (f32x4){0.f,0.f,0.f,0.f}; }
#pragma unroll
        for (int kb = 0; kb < 2; kb++) {
            const int co = ((kb * 4 + quad) ^ sw) * 8;
#pragma unroll
            for (int j = 0; j < 4; j++) {
                sa[j] = mfma16(frag(k1s, j * 16 + lr, co), aq[kb], sa[j]);
                sb[j] = mfma16(frag(k2s, j * 16 + lr, co), aq[kb], sb[j]);
            }
        }

        if (kt < qt) {
#pragma unroll
            for (int j = 0; j < 4; j++)
#pragma unroll
                for (int r = 0; r < 4; r++) {
                    z1 += ex2(sa[j][r]);
                    z2 += ex2(sb[j][r]);
                }
        } else {
#pragma unroll
            for (int j = 0; j < 4; j++)
#pragma unroll
                for (int r = 0; r < 4; r++) {
                    int kglob = kt * 64 + (j >> 1) * 32 + (j & 1) * 4 + quad * 8 + r;
                    if (kglob <= qrow) {
                        z1 += ex2(sa[j][r]);
                        z2 += ex2(sb[j][r]);
                    }
                }
        }
    }

    // reduce across the 4 quads holding the same q-row
    z1 += __shfl_xor(z1, 16, 64); z1 += __shfl_xor(z1, 32, 64);
    z2 += __shfl_xor(z2, 16, 64); z2 += __shfl_xor(z2, 32, 64);
    if (quad == 0) {
        zp[((size_t)(par * 2 + 0) * NH + h) * T_SEQ + qrow] = z1;
        zp[((size_t)(par * 2 + 1) * NH + h) * T_SEQ + qrow] = z2;
    }
}

// ---------------------------------------------------------------------------
// attn_b: P, partial |p| denom, partial O over the kt ≡ par (mod 2) strip.
// r8 version EXACT (best measured, 188.8 total): swapped QK + G-perm K
// staging -> P in registers end-to-end; two-barrier single-buffer schedule,
// 24576 B LDS -> 4+ blocks/CU. (r9's dbuf+vmcnt variant was neutral ->
// reverted per best-known-config discipline.)
// ---------------------------------------------------------------------------
__global__ __launch_bounds__(256) void attn_b(
    const u16* __restrict__ qg, const u16* __restrict__ k1g,
    const u16* __restrict__ k2g, const u16* __restrict__ vtg,
    const float* __restrict__ zp, const void* __restrict__ lamsrc,
    const int* __restrict__ flag,
    float* __restrict__ dpart, u16* __restrict__ opart) {
    __shared__ __align__(16) u16 k1s[64 * 64];
    __shared__ __align__(16) u16 k2s[64 * 64];
    __shared__ __align__(16) u16 vs[64 * 64];
    const int b = blockIdx.x;
    const int x = b & 7;                 // XCD slot
    const int g = b >> 3;                // 0..127
    const int hl = g >> 6;               // 0..1
    const int par = (g >> 5) & 1;        // 0..1
    const int bi = g & 31;
    const int qt = (bi < 16) ? bi : 47 - bi;
    const int h = x * 2 + hl;
    const int t0 = qt * 64;
    ATTN_MAP_COMMON();

    const int f = *flag;
    float lamlogit = f ? bf2f(((const u16*)lamsrc)[h]) : ((const float*)lamsrc)[h];
    const float lam = 1.0f / (1.0f + __expf(-lamlogit));

    const u16* qh = qg + (size_t)h * T_SEQ * HD;
    const u16* k1h = k1g + (size_t)h * T_SEQ * HD;
    const u16* k2h = k2g + (size_t)h * T_SEQ * HD;
    const u16* vh = vtg + (size_t)h * HD * T_SEQ;

    const int qrow = t0 + wm + lr;       // this thread's q-row for P
    bf16x8 aq[2];
#pragma unroll
    for (int kb = 0; kb < 2; kb++)
        aq[kb] = *(const bf16x8*)(&qh[(size_t)qrow * HD + kb * 32 + quad * 8]);

    float zz1 = 0.f, zz2 = 0.f;
#pragma unroll
    for (int p = 0; p < 4; p++) {
        zz1 += zp[((size_t)(p * 2 + 0) * NH + h) * T_SEQ + qrow];
        zz2 += zp[((size_t)(p * 2 + 1) * NH + h) * T_SEQ + qrow];
    }
    const float z1l = -__log2f(zz1);
    const float z2l = __log2f(lam) - __log2f(zz2);

    f32x4 oac[4];
#pragma unroll
    for (int j = 0; j < 4; j++) oac[j] = (f32x4){0.f, 0.f, 0.f, 0.f};
    float dacc = 0.f;

    for (int kt = par; kt <= qt; kt += 2) {
        __syncthreads();
        stage_perm(k1h, (size_t)kt * 64, k1s, tid);
        stage_perm(k2h, (size_t)kt * 64, k2s, tid);
        stage_async<2>(vh, 0, T_SEQ, (size_t)kt * 64, vs, tid);
        __syncthreads();

        f32x4 sa[4], sb[4];
#pragma unroll
        for (int j = 0; j < 4; j++) { sa[j] = (f32x4){0.f,0.f,0.f,0.f}; sb[j] = (f32x4){0.f,0.f,0.f,0.f}; }
#pragma unroll
        for (int kb = 0; kb < 2; kb++) {
            const int co = ((kb * 4 + quad) ^ sw) * 8;
#pragma unroll
            for (int j = 0; j < 4; j++) {
                sa[j] = mfma16(frag(k1s, j * 16 + lr, co), aq[kb], sa[j]);
                sb[j] = mfma16(frag(k2s, j * 16 + lr, co), aq[kb], sb[j]);
            }
        }

        // softmax-difference, all in registers; pt[kh][e] with
        // e = (j&1)*4 + r, k_local = kh*32 + quad*8 + e
        float pt[2][8];
        if (kt < qt) {
#pragma unroll
            for (int j = 0; j < 4; j++)
#pragma unroll
                for (int r = 0; r < 4; r++) {
                    float pv = ex2(sa[j][r] + z1l) - ex2(sb[j][r] + z2l);
                    dacc += fabsf(pv);
                    pt[j >> 1][(j & 1) * 4 + r] = pv;
                }
        } else {
#pragma unroll
            for (int j = 0; j < 4; j++)
#pragma unroll
                for (int r = 0; r < 4; r++) {
                    int kglob = kt * 64 + (j >> 1) * 32 + (j & 1) * 4 + quad * 8 + r;
                    float pv = 0.f;
                    if (kglob <= qrow)
                        pv = ex2(sa[j][r] + z1l) - ex2(sb[j][r] + z2l);
                    dacc += fabsf(pv);
                    pt[j >> 1][(j & 1) * 4 + r] = pv;
                }
        }

        // pack P A-fragments (registers only; truncating bf16 as before)
        bf16x8 pa[2];
#pragma unroll
        for (int kh = 0; kh < 2; kh++) {
            union { u32 w[4]; bf16x8 v; } pk_;
#pragma unroll
            for (int wi = 0; wi < 4; wi++)
                pk_.w[wi] = (u32)f2bf_t(pt[kh][2 * wi]) |
                            ((u32)f2bf_t(pt[kh][2 * wi + 1]) << 16);
            pa[kh] = pk_.v;
        }

        // PV: A = P (in regs), B = V fragments from LDS
#pragma unroll
        for (int kh = 0; kh < 2; kh++) {
            const int co = ((kh * 4 + quad) ^ sw) * 8;
#pragma unroll
            for (int j = 0; j < 4; j++)
                oac[j] = mfma16(pa[kh], frag(vs, j * 16 + lr, co), oac[j]);
        }
    }

    // denom reduce across quads (same q-row), write by quad 0
    float ds = dacc;
    ds += __shfl_xor(ds, 16, 64);
    ds += __shfl_xor(ds, 32, 64);
    if (quad == 0)
        dpart[((size_t)par * NH + h) * T_SEQ + qrow] = ds;

#pragma unroll
    for (int j = 0; j < 4; j++)
#pragma unroll
        for (int r = 0; r < 4; r++) {
            int row = t0 + wm + quad * 4 + r;
            opart[(size_t)par * T_SEQ * DM + (size_t)row * DM + h * HD + j * 16 + lr] =
                f2bf(oac[j][r]);
        }
}

// ---------------------------------------------------------------------------
// normalize: ao[t][d] = (O0+O1) / max(d0+d1, 1e-6).
// ---------------------------------------------------------------------------
__global__ __launch_bounds__(256) void normalize_o(
    const u16* __restrict__ opart, const float* __restrict__ dpart,
    u16* __restrict__ ao) {
    int g = blockIdx.x * 256 + threadIdx.x;
    int t = g >> 7;
    int cc = g & 127;
    int d0 = cc * 8;
    int h = d0 >> 6;
    float dsum = dpart[(size_t)h * T_SEQ + t] + dpart[(size_t)(NH + h) * T_SEQ + t];
    float rs = 1.f / fmaxf(dsum, 1e-6f);
    uint4 a = *(const uint4*)(&opart[(size_t)t * DM + d0]);
    uint4 bqq = *(const uint4*)(&opart[(size_t)T_SEQ * DM + (size_t)t * DM + d0]);
    const u32* au = (const u32*)&a;
    const u32* bu = (const u32*)&bqq;
    uint4 out;
    u32* ou = (u32*)&out;
#pragma unroll
    for (int i = 0; i < 4; i++) {
        float lo = (bf2f((u16)(au[i] & 0xFFFF)) + bf2f((u16)(bu[i] & 0xFFFF))) * rs;
        float hi = (bf2f((u16)(au[i] >> 16)) + bf2f((u16)(bu[i] >> 16))) * rs;
        ou[i] = pk2(lo, hi);
    }
    *(uint4*)(&ao[(size_t)t * DM + d0]) = out;
}

// ---------------------------------------------------------------------------
// Output GEMM: out = ao @ Wo^T. Tile 64x64 -> grid (16,32) = 512 blocks =
// 2 blocks/CU. Always-async dbuf staging. (unchanged)
// ---------------------------------------------------------------------------
__global__ __launch_bounds__(256) void out_gemm(
    const u16* __restrict__ ab, const void* __restrict__ wo0,
    const u16* __restrict__ woc, const int* __restrict__ flag,
    void* __restrict__ outp) {
    __shared__ __align__(16) u16 As[2][64 * 64];
    __shared__ __align__(16) u16 Bs[2][64 * 64];

    const int f = *flag;   // 1 = bf16 in/out
    const u16* wb = f ? (const u16*)wo0 : woc;
    const int n0 = blockIdx.x * 64;    // 0..15
    const int m0 = blockIdx.y * 64;    // 0..31
    const int tid = threadIdx.x;
    const int lane = tid & 63, wave = tid >> 6;
    const int lr = lane & 15, quad = lane >> 4;
    const int wm = (wave >> 1) * 32, wn = (wave & 1) * 32;
    const int sw = lr & 7;

    f32x4 acc[2][2];
#pragma unroll
    for (int i = 0; i < 2; i++)
#pragma unroll
        for (int j = 0; j < 2; j++) acc[i][j] = (f32x4){0.f, 0.f, 0.f, 0.f};

    stage_async<2>(ab, m0, DM, 0, As[0], tid);
    stage_async<2>(wb, n0, DM, 0, Bs[0], tid);
    for (int k0 = 0; k0 < DM; k0 += 64) {
        const int cur = (k0 >> 6) & 1;
        __syncthreads();
        if (k0 + 64 < DM) {
            stage_async<2>(ab, m0, DM, k0 + 64, As[cur ^ 1], tid);
            stage_async<2>(wb, n0, DM, k0 + 64, Bs[cur ^ 1], tid);
        }
#pragma unroll
        for (int kk = 0; kk < 2; kk++) {
            const int co = ((kk * 4 + quad) ^ sw) * 8;
            bf16x8 af[2], bfr[2];
#pragma unroll
            for (int i = 0; i < 2; i++) af[i] = frag(As[cur], wm + i * 16 + lr, co);
#pragma unroll
            for (int j = 0; j < 2; j++) bfr[j] = frag(Bs[cur], wn + j * 16 + lr, co);
#pragma unroll
            for (int i = 0; i < 2; i++)
#pragma unroll
                for (int j = 0; j < 2; j++) acc[i][j] = mfma16(af[i], bfr[j], acc[i][j]);
        }
    }

#pragma unroll
    for (int i = 0; i < 2; i++)
#pragma unroll
        for (int j = 0; j < 2; j++)
#pragma unroll
            for (int r = 0; r < 4; r++) {
                int t = m0 + wm + i * 16 + quad * 4 + r;
                int o = n0 + wn + j * 16 + lr;
                float val = acc[i][j][r];
                if (f)
                    ((u16*)outp)[(size_t)t * DM + o] = f2bf(val);
                else
                    ((float*)outp)[(size_t)t * DM + o] = val;
            }
}

extern "C" void kernel_launch(void* const* d_in, const int* in_sizes, int n_in,
                              void* d_out, int out_size, void* d_ws, size_t ws_size,
                              hipStream_t stream) {
    char* ws = (char*)d_ws;
    int* flag = (int*)(ws + 0);
    float* zp    = (float*)(ws + ((size_t)1 << 20));   // [8][NH][T] f32 = 1 MB
    float* dpart = (float*)(ws + ((size_t)2 << 20));   // [2][NH][T] f32
    u16* qd  = (u16*)(ws + ((size_t)16 << 20));  // [H][T][64]
    u16* k1d = (u16*)(ws + ((size_t)20 << 20));
    u16* k2d = (u16*)(ws + ((size_t)24 << 20));
    u16* vtd = (u16*)(ws + ((size_t)28 << 20));  // [H][64][T]
    u16* ao  = (u16*)(ws + ((size_t)32 << 20));  // [T][DM] bf16
    u16* opart = (u16*)(ws + ((size_t)36 << 20)); // [2][T][DM] bf16
    // bf16-converted inputs (only written when source is f32)
    u16* xc   = (u16*)(ws + ((size_t)44 << 20)); // [T][DM]   4 MB
    u16* wqc  = (u16*)(ws + ((size_t)48 << 20)); // [DM][DM]  2 MB each
    u16* wk1c = (u16*)(ws + ((size_t)50 << 20));
    u16* wk2c = (u16*)(ws + ((size_t)52 << 20));
    u16* wvc  = (u16*)(ws + ((size_t)54 << 20));
    u16* woc  = (u16*)(ws + ((size_t)56 << 20));

    detect_dtype<<<dim3(1), 256, 0, stream>>>((const u16*)d_in[0], flag);
    cvt_bf16<<<dim3(3584), 256, 0, stream>>>(
        flag, (const float*)d_in[0], (const float*)d_in[1], (const float*)d_in[2],
        (const float*)d_in[3], (const float*)d_in[4], (const float*)d_in[5],
        xc, wqc, wk1c, wk2c, wvc, woc);
    qkv_gemm<<<dim3(32, 16), 256, 0, stream>>>(
        flag, d_in[0], d_in[1], d_in[2], d_in[3], d_in[4],
        xc, wqc, wk1c, wk2c, wvc, qd, k1d, k2d, vtd);
    attn_a<<<dim3(2048), 256, 0, stream>>>(qd, k1d, k2d, zp);
    attn_b<<<dim3(1024), 256, 0, stream>>>(qd, k1d, k2d, vtd, zp, d_in[6], flag,
                                           dpart, opart);
    normalize_o<<<dim3(1024), 256, 0, stream>>>(opart, dpart, ao);
    out_gemm<<<dim3(16, 32), 256, 0, stream>>>(ao, d_in[5], woc, flag, d_out);
}